// Round 3
// baseline (226.181 us; speedup 1.0000x reference)
//
#include <hip/hip_runtime.h>

// Batched gather-GEMV:
//   out[bp, d] = (sum_h hs[bp, h] * W[props[bp], h, d] + bias[props[bp], d]) * mask[bp]
// B*P = 65536, H = 512, D = 2.
//
// One wave per (b,p) pair. Lane i, chunk j (j=0,1) owns h = 256j+4i .. 256j+4i+3:
//   hs: float4  hs4[bp*128  + 64j + i]          (lane-contiguous, 1 KiB/instr)
//   W : float4  w4[prop*256 + 2*(64j+... )]      (two dwordx4, 32B lane stride)
// 6 data loads/lane (was 8). props issued first; hs loads overlap the props
// miss; W/bias/mask issued together at dependency depth 1.
// Memory floor ~28 us (hs 134 MB + W 41 MB unique; L3 absorbs gather re-reads).

#define H 512
#define D 2

__global__ __launch_bounds__(256) void adapter_gemv_kernel(
    const float* __restrict__ hs,     // (BP, H)
    const int*   __restrict__ props,  // (BP)
    const float* __restrict__ mask,   // (BP)
    const float* __restrict__ W,      // (NPROP, H, D)
    const float* __restrict__ bias,   // (NPROP, D)
    float* __restrict__ out,          // (BP, D)
    int BP)
{
    const int tid  = blockIdx.x * blockDim.x + threadIdx.x;
    const int bp   = tid >> 6;
    const int lane = tid & 63;
    if (bp >= BP) return;

    // Depth-0 loads: props + hs (independent of props, overlap its latency).
    const int prop = props[bp];
    const float4* h4 = (const float4*)(hs + (size_t)bp * H);   // 128 float4
    float4 ha = h4[lane];         // h = 4i   .. 4i+3
    float4 hb = h4[64 + lane];    // h = 256+4i .. 256+4i+3

    // Depth-1 loads: W, bias, mask (mask is depth-0 but cheap; group issue).
    const float4* w4 = (const float4*)(W + (size_t)prop * (H * D)); // 256 float4
    const int k0 = 2 * lane;          // covers h = 4i, 4i+1
    const int k1 = 128 + 2 * lane;    // covers h = 256+4i, 256+4i+1
    float4 wa0 = w4[k0];
    float4 wa1 = w4[k0 + 1];
    float4 wb0 = w4[k1];
    float4 wb1 = w4[k1 + 1];
    const float2 bv = *(const float2*)(bias + (size_t)prop * D);
    const float  m  = mask[bp];

    // w4[k] packs (W[2k,0], W[2k,1], W[2k+1,0], W[2k+1,1]).
    float s0 = ha.x * wa0.x + ha.y * wa0.z + ha.z * wa1.x + ha.w * wa1.z
             + hb.x * wb0.x + hb.y * wb0.z + hb.z * wb1.x + hb.w * wb1.z;
    float s1 = ha.x * wa0.y + ha.y * wa0.w + ha.z * wa1.y + ha.w * wa1.w
             + hb.x * wb0.y + hb.y * wb0.w + hb.z * wb1.y + hb.w * wb1.w;

    // 64-lane butterfly reduction
    #pragma unroll
    for (int off = 32; off > 0; off >>= 1) {
        s0 += __shfl_xor(s0, off, 64);
        s1 += __shfl_xor(s1, off, 64);
    }

    if (lane == 0) {
        float2 r;
        r.x = (s0 + bv.x) * m;
        r.y = (s1 + bv.y) * m;
        *(float2*)(out + (size_t)bp * D) = r;
    }
}

extern "C" void kernel_launch(void* const* d_in, const int* in_sizes, int n_in,
                              void* d_out, int out_size, void* d_ws, size_t ws_size,
                              hipStream_t stream) {
    const float* hs    = (const float*)d_in[0];
    const int*   props = (const int*)d_in[1];
    const float* mask  = (const float*)d_in[2];
    const float* W     = (const float*)d_in[3];
    const float* bias  = (const float*)d_in[4];
    float* out = (float*)d_out;

    const int BP = in_sizes[1];          // 512 * 128 = 65536 pairs
    const int threads = 256;             // 4 waves/block
    const int waves_per_block = threads / 64;
    const int blocks = (BP + waves_per_block - 1) / waves_per_block;

    adapter_gemv_kernel<<<blocks, threads, 0, stream>>>(hs, props, mask, W, bias, out, BP);
}